// Round 2
// baseline (493.440 us; speedup 1.0000x reference)
//
#include <hip/hip_runtime.h>
#include <hip/hip_bf16.h>

#define E_ 8
#define H_ 2048
#define I_ 1408
#define S_ 2048       // B*S tokens
#define NPAIR 4096    // S_*K
#define MAXMT 32      // worst-case M-tiles per expert (4096/128)

#define NT1 22        // (2*I_)/128 weight row-tiles for gate_up
#define KT1 64        // H_/32
#define NT2 16        // H_/128 weight row-tiles for down
#define KT2 44        // I_/32

typedef short bf16x8 __attribute__((ext_vector_type(8)));
typedef ushort u16x8 __attribute__((ext_vector_type(8)));
typedef float f32x4  __attribute__((ext_vector_type(4)));

__device__ inline bf16x8 pack8(float4 a, float4 b) {
    bf16x8 r;
    const float v[8] = {a.x, a.y, a.z, a.w, b.x, b.y, b.z, b.w};
#pragma unroll
    for (int j = 0; j < 8; ++j) {
        __hip_bfloat16 t = __float2bfloat16(v[j]);
        r[j] = *reinterpret_cast<short*>(&t);
    }
    return r;
}

// async global->LDS, 16B per lane; LDS dest linear (base + lane*16)
__device__ __forceinline__ void gload16(const ushort* g, ushort* l) {
    __builtin_amdgcn_global_load_lds(
        (const __attribute__((address_space(1))) void*)g,
        (__attribute__((address_space(3))) void*)l,
        16, 0, 0);
}

// ---------------------------------------------------------------- router ----
__global__ void moe_router(const int* __restrict__ idx,
                           int* __restrict__ counts, int* __restrict__ bases,
                           int* __restrict__ tok, int* __restrict__ inv) {
    __shared__ int cnt[E_];
    __shared__ int cur[E_];
    const int tid = threadIdx.x;
    if (tid < E_) cnt[tid] = 0;
    __syncthreads();
    for (int p = tid; p < NPAIR; p += 256)
        atomicAdd(&cnt[idx[p]], 1);
    __syncthreads();
    if (tid == 0) {
        int b = 0;
        for (int e = 0; e < E_; ++e) {
            counts[e] = cnt[e];
            bases[e]  = b;
            cur[e]    = b;
            b += cnt[e];
        }
    }
    __syncthreads();
    for (int p = tid; p < NPAIR; p += 256) {
        const int e = idx[p];
        const int pos = atomicAdd(&cur[e], 1);
        tok[pos] = p >> 1;   // token id (K=2)
        inv[p]   = pos;      // pair -> sorted position
    }
}

// ------------------------------------------------------------- convert x ----
__global__ void convert_x(const float* __restrict__ x, ushort* __restrict__ xb) {
    const size_t i = ((size_t)blockIdx.x * 256 + threadIdx.x) * 8;
    const float4 a = *(const float4*)(x + i);
    const float4 b = *(const float4*)(x + i + 4);
    *(bf16x8*)(xb + i) = pack8(a, b);
}

// ------------------------------------------------------- convert weights ----
// fp32 -> bf16, re-tiled: wgt[e][nt][kt][128][32], wdt[e][nt][kt][128][32]
__global__ __launch_bounds__(256)
void convert_w(const float* __restrict__ wg, const float* __restrict__ wd,
               ushort* __restrict__ wgt, ushort* __restrict__ wdt) {
    const int b = blockIdx.x;
    const int tid = threadIdx.x;
    const float* src;
    ushort* dst;
    int rowstride;
    if (b < E_ * NT1 * KT1) {
        const int e = b / (NT1 * KT1), rem = b % (NT1 * KT1);
        const int nt = rem / KT1, kt = rem % KT1;
        src = wg + ((size_t)e * (2 * I_) + nt * 128) * H_ + kt * 32;
        dst = wgt + (size_t)b * 4096;
        rowstride = H_;
    } else {
        const int b2 = b - E_ * NT1 * KT1;
        const int e = b2 / (NT2 * KT2), rem = b2 % (NT2 * KT2);
        const int nt = rem / KT2, kt = rem % KT2;
        src = wd + ((size_t)e * H_ + nt * 128) * I_ + kt * 32;
        dst = wdt + (size_t)b2 * 4096;
        rowstride = I_;
    }
#pragma unroll
    for (int i = 0; i < 2; ++i) {
        const int c = tid + i * 256;
        const int row = c >> 2, col = (c & 3) * 8;
        const float* s = src + (size_t)row * rowstride + col;
        const float4 a = *(const float4*)s;
        const float4 bq = *(const float4*)(s + 4);
        *(bf16x8*)(dst + c * 8) = pack8(a, bq);
    }
}

// ------------------------------------------------ GEMM1 (bf16 weights) ----
__global__ __launch_bounds__(256, 2)
void moe_gemm1(const ushort* __restrict__ xb,
               const ushort* __restrict__ wgt,
               const int* __restrict__ counts,
               const int* __restrict__ bases,
               const int* __restrict__ tok,
               ushort* __restrict__ hbuf) {
    const int e  = blockIdx.y & (E_ - 1);
    const int mt = blockIdx.y >> 3;
    const int count = counts[e];
    if (mt * 128 >= count) return;
    const int base = bases[e];
    const int nt = blockIdx.x;           // 0..10
    const int n0 = nt * 128;

    __shared__ alignas(16) ushort sm[17408];   // 34 KB (epilogue needs 128*136)
    ushort* smA = sm;              // [128][32] bf16, linear
    ushort* smG = sm + 4096;
    ushort* smU = sm + 8192;

    const int tid  = threadIdx.x;
    const int lane = tid & 63;
    const int wid  = tid >> 6;
    const int wm = wid & 1, wn = wid >> 1;
    const int lr = lane & 15, lq = lane >> 4;

    const f32x4 vzero = {0.f, 0.f, 0.f, 0.f};
    f32x4 accg[4][4], accu[4][4];
#pragma unroll
    for (int mi = 0; mi < 4; ++mi)
#pragma unroll
        for (int ni = 0; ni < 4; ++ni) { accg[mi][ni] = vzero; accu[mi][ni] = vzero; }

    const int srow = tid >> 2;          // 0..63
    const int sc8  = (tid & 3) * 8;     // element col 0,8,16,24
    const int ia0 = mt * 128 + srow, ia1 = ia0 + 64;
    const ushort* ap0 = xb + (size_t)(ia0 < count ? tok[base + ia0] : 0) * H_ + sc8;
    const ushort* ap1 = xb + (size_t)(ia1 < count ? tok[base + ia1] : 0) * H_ + sc8;
    const ushort* gp  = wgt + (size_t)(e * NT1 + nt) * KT1 * 4096 + tid * 8;
    const ushort* up  = wgt + (size_t)(e * NT1 + nt + 11) * KT1 * 4096 + tid * 8;
    ushort* dA0 = smA + tid * 8;
    ushort* dA1 = smA + tid * 8 + 2048;
    ushort* dG0 = smG + tid * 8;
    ushort* dG1 = smG + tid * 8 + 2048;
    ushort* dU0 = smU + tid * 8;
    ushort* dU1 = smU + tid * 8 + 2048;

    for (int kt = 0; kt < KT1; ++kt) {
        gload16(ap0, dA0);
        gload16(ap1, dA1);
        gload16(gp,        dG0);
        gload16(gp + 2048, dG1);
        gload16(up,        dU0);
        gload16(up + 2048, dU1);
        ap0 += 32; ap1 += 32; gp += 4096; up += 4096;
        __syncthreads();                 // drains vmcnt(0) before barrier

        bf16x8 a[4], bg[4], bu[4];
#pragma unroll
        for (int mi = 0; mi < 4; ++mi)
            a[mi] = *(const bf16x8*)&smA[(wm * 64 + mi * 16 + lr) * 32 + lq * 8];
#pragma unroll
        for (int ni = 0; ni < 4; ++ni) {
            bg[ni] = *(const bf16x8*)&smG[(wn * 64 + ni * 16 + lr) * 32 + lq * 8];
            bu[ni] = *(const bf16x8*)&smU[(wn * 64 + ni * 16 + lr) * 32 + lq * 8];
        }
#pragma unroll
        for (int mi = 0; mi < 4; ++mi)
#pragma unroll
            for (int ni = 0; ni < 4; ++ni) {
                accg[mi][ni] = __builtin_amdgcn_mfma_f32_16x16x32_bf16(a[mi], bg[ni], accg[mi][ni], 0, 0, 0);
                accu[mi][ni] = __builtin_amdgcn_mfma_f32_16x16x32_bf16(a[mi], bu[ni], accu[mi][ni], 0, 0, 0);
            }
        __syncthreads();
    }

    ushort* Ht = sm;
#pragma unroll
    for (int mi = 0; mi < 4; ++mi)
#pragma unroll
        for (int r = 0; r < 4; ++r) {
            const int row = wm * 64 + mi * 16 + lq * 4 + r;
#pragma unroll
            for (int ni = 0; ni < 4; ++ni) {
                const int col = wn * 64 + ni * 16 + lr;
                const float g = accg[mi][ni][r];
                const float u = accu[mi][ni][r];
                const float h = (g / (1.0f + __expf(-g))) * u;
                __hip_bfloat16 hb = __float2bfloat16(h);
                Ht[row * 136 + col] = *reinterpret_cast<ushort*>(&hb);
            }
        }
    __syncthreads();
#pragma unroll
    for (int p = 0; p < 8; ++p) {
        const int slot = p * 256 + tid;
        const int row = slot >> 4;
        const int cc  = (slot & 15) * 8;
        const int gi = mt * 128 + row;
        if (gi < count)
            *(uint4*)&hbuf[(size_t)(base + gi) * I_ + n0 + cc] = *(const uint4*)&Ht[row * 136 + cc];
    }
}

// ------------------------------------------------ GEMM2 (bf16 weights) ----
__global__ __launch_bounds__(256, 2)
void moe_gemm2(const ushort* __restrict__ hbuf,
               const ushort* __restrict__ wdt,
               const int* __restrict__ counts,
               const int* __restrict__ bases,
               ushort* __restrict__ ybuf) {
    const int e  = blockIdx.y & (E_ - 1);
    const int mt = blockIdx.y >> 3;
    const int count = counts[e];
    if (mt * 128 >= count) return;
    const int base = bases[e];
    const int nt = blockIdx.x;           // 0..15
    const int n0 = nt * 128;

    __shared__ alignas(16) ushort sm[17408];   // 34 KB
    ushort* smA = sm;              // [128][32]
    ushort* smB = sm + 4096;

    const int tid  = threadIdx.x;
    const int lane = tid & 63;
    const int wid  = tid >> 6;
    const int wm = wid & 1, wn = wid >> 1;
    const int lr = lane & 15, lq = lane >> 4;

    const f32x4 vzero = {0.f, 0.f, 0.f, 0.f};
    f32x4 acc[4][4];
#pragma unroll
    for (int mi = 0; mi < 4; ++mi)
#pragma unroll
        for (int ni = 0; ni < 4; ++ni) acc[mi][ni] = vzero;

    const int srow = tid >> 2;
    const int sc8  = (tid & 3) * 8;
    const int ia0 = mt * 128 + srow, ia1 = ia0 + 64;
    const ushort* ap0 = hbuf + (size_t)(base + (ia0 < count ? ia0 : 0)) * I_ + sc8;
    const ushort* ap1 = hbuf + (size_t)(base + (ia1 < count ? ia1 : 0)) * I_ + sc8;
    const ushort* bp  = wdt + (size_t)(e * NT2 + nt) * KT2 * 4096 + tid * 8;
    ushort* dA0 = smA + tid * 8;
    ushort* dA1 = smA + tid * 8 + 2048;
    ushort* dB0 = smB + tid * 8;
    ushort* dB1 = smB + tid * 8 + 2048;

    for (int kt = 0; kt < KT2; ++kt) {
        gload16(ap0, dA0);
        gload16(ap1, dA1);
        gload16(bp,        dB0);
        gload16(bp + 2048, dB1);
        ap0 += 32; ap1 += 32; bp += 4096;
        __syncthreads();

        bf16x8 a[4], b[4];
#pragma unroll
        for (int mi = 0; mi < 4; ++mi)
            a[mi] = *(const bf16x8*)&smA[(wm * 64 + mi * 16 + lr) * 32 + lq * 8];
#pragma unroll
        for (int ni = 0; ni < 4; ++ni)
            b[ni] = *(const bf16x8*)&smB[(wn * 64 + ni * 16 + lr) * 32 + lq * 8];
#pragma unroll
        for (int mi = 0; mi < 4; ++mi)
#pragma unroll
            for (int ni = 0; ni < 4; ++ni)
                acc[mi][ni] = __builtin_amdgcn_mfma_f32_16x16x32_bf16(a[mi], b[ni], acc[mi][ni], 0, 0, 0);
        __syncthreads();
    }

    ushort* Yt = sm;
#pragma unroll
    for (int mi = 0; mi < 4; ++mi)
#pragma unroll
        for (int r = 0; r < 4; ++r) {
            const int row = wm * 64 + mi * 16 + lq * 4 + r;
#pragma unroll
            for (int ni = 0; ni < 4; ++ni) {
                const int col = wn * 64 + ni * 16 + lr;
                __hip_bfloat16 yb = __float2bfloat16(acc[mi][ni][r]);
                Yt[row * 136 + col] = *reinterpret_cast<ushort*>(&yb);
            }
        }
    __syncthreads();
#pragma unroll
    for (int p = 0; p < 8; ++p) {
        const int slot = p * 256 + tid;
        const int row = slot >> 4;
        const int cc  = (slot & 15) * 8;
        const int gi = mt * 128 + row;
        if (gi < count)
            *(uint4*)&ybuf[(size_t)(base + gi) * H_ + n0 + cc] = *(const uint4*)&Yt[row * 136 + cc];
    }
}

// --------------------------- FALLBACK GEMM1 (fp32 weights, verified 426us) --
__global__ __launch_bounds__(256, 2)
void moe_gemm1_f32(const ushort* __restrict__ xb,
                   const float* __restrict__ wg,
                   const int* __restrict__ counts,
                   const int* __restrict__ bases,
                   const int* __restrict__ tok,
                   ushort* __restrict__ hbuf) {
    const int e  = blockIdx.y & (E_ - 1);
    const int mt = blockIdx.y >> 3;
    const int count = counts[e];
    if (mt * 128 >= count) return;
    const int base = bases[e];
    const int n0 = blockIdx.x * 128;
    const float* wge = wg + (size_t)e * (2 * I_) * H_;

    __shared__ alignas(16) ushort sm[2][3][5120];   // 60 KB

    const int tid  = threadIdx.x;
    const int lane = tid & 63;
    const int wid  = tid >> 6;
    const int wm = wid & 1, wn = wid >> 1;
    const int lr = lane & 15, lq = lane >> 4;

    const f32x4 vzero = {0.f, 0.f, 0.f, 0.f};
    f32x4 accg[4][4], accu[4][4];
#pragma unroll
    for (int mi = 0; mi < 4; ++mi)
#pragma unroll
        for (int ni = 0; ni < 4; ++ni) { accg[mi][ni] = vzero; accu[mi][ni] = vzero; }

    const int srow = tid >> 2;
    const int sc8  = (tid & 3) * 8;
    const int r0 = srow, r1 = srow + 64;

    const int ia0 = mt * 128 + r0, ia1 = mt * 128 + r1;
    const bool v0 = ia0 < count, v1 = ia1 < count;
    const ushort* ap0 = xb + (size_t)(v0 ? tok[base + ia0] : 0) * H_ + sc8;
    const ushort* ap1 = xb + (size_t)(v1 ? tok[base + ia1] : 0) * H_ + sc8;
    const float* gp0 = wge + (size_t)(n0 + r0) * H_ + sc8;
    const float* gp1 = wge + (size_t)(n0 + r1) * H_ + sc8;
    const float* up0 = gp0 + (size_t)I_ * H_;
    const float* up1 = gp1 + (size_t)I_ * H_;

    const uint4 z4 = {0u, 0u, 0u, 0u};
    uint4 ra0, ra1;
    float4 rg0a, rg0b, rg1a, rg1b, ru0a, ru0b, ru1a, ru1b;

    ra0 = v0 ? *(const uint4*)ap0 : z4;
    ra1 = v1 ? *(const uint4*)ap1 : z4;
    rg0a = *(const float4*)gp0; rg0b = *(const float4*)(gp0 + 4);
    rg1a = *(const float4*)gp1; rg1b = *(const float4*)(gp1 + 4);
    ru0a = *(const float4*)up0; ru0b = *(const float4*)(up0 + 4);
    ru1a = *(const float4*)up1; ru1b = *(const float4*)(up1 + 4);
    {
        ushort* As = &sm[0][0][0]; ushort* Bg = &sm[0][1][0]; ushort* Bu = &sm[0][2][0];
        *(uint4*)&As[r0 * 40 + sc8] = ra0;
        *(uint4*)&As[r1 * 40 + sc8] = ra1;
        *(bf16x8*)&Bg[r0 * 40 + sc8] = pack8(rg0a, rg0b);
        *(bf16x8*)&Bg[r1 * 40 + sc8] = pack8(rg1a, rg1b);
        *(bf16x8*)&Bu[r0 * 40 + sc8] = pack8(ru0a, ru0b);
        *(bf16x8*)&Bu[r1 * 40 + sc8] = pack8(ru1a, ru1b);
    }
    __syncthreads();

    for (int kt = 0; kt < H_ / 32; ++kt) {
        const int cur = kt & 1;
        if (kt < H_ / 32 - 1) {
            ap0 += 32; ap1 += 32; gp0 += 32; gp1 += 32; up0 += 32; up1 += 32;
            ra0 = v0 ? *(const uint4*)ap0 : z4;
            ra1 = v1 ? *(const uint4*)ap1 : z4;
            rg0a = *(const float4*)gp0; rg0b = *(const float4*)(gp0 + 4);
            rg1a = *(const float4*)gp1; rg1b = *(const float4*)(gp1 + 4);
            ru0a = *(const float4*)up0; ru0b = *(const float4*)(up0 + 4);
            ru1a = *(const float4*)up1; ru1b = *(const float4*)(up1 + 4);
        }
        const ushort* As = &sm[cur][0][0];
        const ushort* Bg = &sm[cur][1][0];
        const ushort* Bu = &sm[cur][2][0];
        bf16x8 a[4], bg[4], bu[4];
#pragma unroll
        for (int mi = 0; mi < 4; ++mi)
            a[mi] = *(const bf16x8*)&As[(wm * 64 + mi * 16 + lr) * 40 + lq * 8];
#pragma unroll
        for (int ni = 0; ni < 4; ++ni) {
            bg[ni] = *(const bf16x8*)&Bg[(wn * 64 + ni * 16 + lr) * 40 + lq * 8];
            bu[ni] = *(const bf16x8*)&Bu[(wn * 64 + ni * 16 + lr) * 40 + lq * 8];
        }
#pragma unroll
        for (int mi = 0; mi < 4; ++mi)
#pragma unroll
            for (int ni = 0; ni < 4; ++ni) {
                accg[mi][ni] = __builtin_amdgcn_mfma_f32_16x16x32_bf16(a[mi], bg[ni], accg[mi][ni], 0, 0, 0);
                accu[mi][ni] = __builtin_amdgcn_mfma_f32_16x16x32_bf16(a[mi], bu[ni], accu[mi][ni], 0, 0, 0);
            }
        if (kt < H_ / 32 - 1) {
            ushort* nA = &sm[cur ^ 1][0][0];
            ushort* nG = &sm[cur ^ 1][1][0];
            ushort* nU = &sm[cur ^ 1][2][0];
            *(uint4*)&nA[r0 * 40 + sc8] = ra0;
            *(uint4*)&nA[r1 * 40 + sc8] = ra1;
            *(bf16x8*)&nG[r0 * 40 + sc8] = pack8(rg0a, rg0b);
            *(bf16x8*)&nG[r1 * 40 + sc8] = pack8(rg1a, rg1b);
            *(bf16x8*)&nU[r0 * 40 + sc8] = pack8(ru0a, ru0b);
            *(bf16x8*)&nU[r1 * 40 + sc8] = pack8(ru1a, ru1b);
        }
        __syncthreads();
    }

    ushort* Ht = &sm[0][0][0];
#pragma unroll
    for (int mi = 0; mi < 4; ++mi)
#pragma unroll
        for (int r = 0; r < 4; ++r) {
            const int row = wm * 64 + mi * 16 + lq * 4 + r;
#pragma unroll
            for (int ni = 0; ni < 4; ++ni) {
                const int col = wn * 64 + ni * 16 + lr;
                const float g = accg[mi][ni][r];
                const float u = accu[mi][ni][r];
                const float h = (g / (1.0f + __expf(-g))) * u;
                __hip_bfloat16 hb = __float2bfloat16(h);
                Ht[row * 136 + col] = *reinterpret_cast<ushort*>(&hb);
            }
        }
    __syncthreads();
#pragma unroll
    for (int p = 0; p < 8; ++p) {
        const int slot = p * 256 + tid;
        const int row = slot >> 4;
        const int cc  = (slot & 15) * 8;
        const int gi = mt * 128 + row;
        if (gi < count)
            *(uint4*)&hbuf[(size_t)(base + gi) * I_ + n0 + cc] = *(const uint4*)&Ht[row * 136 + cc];
    }
}

// --------------------------- FALLBACK GEMM2 (fp32 weights, verified 426us) --
__global__ __launch_bounds__(256, 2)
void moe_gemm2_f32(const ushort* __restrict__ hbuf,
                   const float* __restrict__ wd,
                   const int* __restrict__ counts,
                   const int* __restrict__ bases,
                   ushort* __restrict__ ybuf) {
    const int e  = blockIdx.y & (E_ - 1);
    const int mt = blockIdx.y >> 3;
    const int count = counts[e];
    if (mt * 128 >= count) return;
    const int base = bases[e];
    const int n0 = blockIdx.x * 128;
    const float* wde = wd + (size_t)e * H_ * I_;

    __shared__ alignas(16) ushort sm[2][2][5120];   // 40 KB

    const int tid  = threadIdx.x;
    const int lane = tid & 63;
    const int wid  = tid >> 6;
    const int wm = wid & 1, wn = wid >> 1;
    const int lr = lane & 15, lq = lane >> 4;

    const f32x4 vzero = {0.f, 0.f, 0.f, 0.f};
    f32x4 acc[4][4];
#pragma unroll
    for (int mi = 0; mi < 4; ++mi)
#pragma unroll
        for (int ni = 0; ni < 4; ++ni) acc[mi][ni] = vzero;

    const int srow = tid >> 2;
    const int sc8  = (tid & 3) * 8;
    const int r0 = srow, r1 = srow + 64;

    const int ia0 = mt * 128 + r0, ia1 = mt * 128 + r1;
    const bool v0 = ia0 < count, v1 = ia1 < count;
    const ushort* ap0 = hbuf + (size_t)(base + (v0 ? ia0 : 0)) * I_ + sc8;
    const ushort* ap1 = hbuf + (size_t)(base + (v1 ? ia1 : 0)) * I_ + sc8;
    const float* bp0 = wde + (size_t)(n0 + r0) * I_ + sc8;
    const float* bp1 = wde + (size_t)(n0 + r1) * I_ + sc8;

    const uint4 z4 = {0u, 0u, 0u, 0u};
    uint4 ra0, ra1;
    float4 rb0a, rb0b, rb1a, rb1b;

    ra0 = v0 ? *(const uint4*)ap0 : z4;
    ra1 = v1 ? *(const uint4*)ap1 : z4;
    rb0a = *(const float4*)bp0; rb0b = *(const float4*)(bp0 + 4);
    rb1a = *(const float4*)bp1; rb1b = *(const float4*)(bp1 + 4);
    {
        ushort* As = &sm[0][0][0]; ushort* Bs = &sm[0][1][0];
        *(uint4*)&As[r0 * 40 + sc8] = ra0;
        *(uint4*)&As[r1 * 40 + sc8] = ra1;
        *(bf16x8*)&Bs[r0 * 40 + sc8] = pack8(rb0a, rb0b);
        *(bf16x8*)&Bs[r1 * 40 + sc8] = pack8(rb1a, rb1b);
    }
    __syncthreads();

    for (int kt = 0; kt < I_ / 32; ++kt) {
        const int cur = kt & 1;
        if (kt < I_ / 32 - 1) {
            ap0 += 32; ap1 += 32; bp0 += 32; bp1 += 32;
            ra0 = v0 ? *(const uint4*)ap0 : z4;
            ra1 = v1 ? *(const uint4*)ap1 : z4;
            rb0a = *(const float4*)bp0; rb0b = *(const float4*)(bp0 + 4);
            rb1a = *(const float4*)bp1; rb1b = *(const float4*)(bp1 + 4);
        }
        const ushort* As = &sm[cur][0][0];
        const ushort* Bs = &sm[cur][1][0];
        bf16x8 a[4], b[4];
#pragma unroll
        for (int mi = 0; mi < 4; ++mi)
            a[mi] = *(const bf16x8*)&As[(wm * 64 + mi * 16 + lr) * 40 + lq * 8];
#pragma unroll
        for (int ni = 0; ni < 4; ++ni)
            b[ni] = *(const bf16x8*)&Bs[(wn * 64 + ni * 16 + lr) * 40 + lq * 8];
#pragma unroll
        for (int mi = 0; mi < 4; ++mi)
#pragma unroll
            for (int ni = 0; ni < 4; ++ni)
                acc[mi][ni] = __builtin_amdgcn_mfma_f32_16x16x32_bf16(a[mi], b[ni], acc[mi][ni], 0, 0, 0);
        if (kt < I_ / 32 - 1) {
            ushort* nA = &sm[cur ^ 1][0][0];
            ushort* nB = &sm[cur ^ 1][1][0];
            *(uint4*)&nA[r0 * 40 + sc8] = ra0;
            *(uint4*)&nA[r1 * 40 + sc8] = ra1;
            *(bf16x8*)&nB[r0 * 40 + sc8] = pack8(rb0a, rb0b);
            *(bf16x8*)&nB[r1 * 40 + sc8] = pack8(rb1a, rb1b);
        }
        __syncthreads();
    }

    ushort* Yt = &sm[0][0][0];
#pragma unroll
    for (int mi = 0; mi < 4; ++mi)
#pragma unroll
        for (int r = 0; r < 4; ++r) {
            const int row = wm * 64 + mi * 16 + lq * 4 + r;
#pragma unroll
            for (int ni = 0; ni < 4; ++ni) {
                const int col = wn * 64 + ni * 16 + lr;
                __hip_bfloat16 yb = __float2bfloat16(acc[mi][ni][r]);
                Yt[row * 136 + col] = *reinterpret_cast<ushort*>(&yb);
            }
        }
    __syncthreads();
#pragma unroll
    for (int p = 0; p < 8; ++p) {
        const int slot = p * 256 + tid;
        const int row = slot >> 4;
        const int cc  = (slot & 15) * 8;
        const int gi = mt * 128 + row;
        if (gi < count)
            *(uint4*)&ybuf[(size_t)(base + gi) * H_ + n0 + cc] = *(const uint4*)&Yt[row * 136 + cc];
    }
}

// --------------------------------------------------------------- combine ----
__global__ void moe_combine(const ushort* __restrict__ ybuf,
                            const int* __restrict__ inv,
                            const float* __restrict__ tkw,
                            float* __restrict__ out) {
    const int t = blockIdx.x;
    const int c8 = threadIdx.x * 8;
    const int p0 = inv[2 * t], p1 = inv[2 * t + 1];
    const float w0 = tkw[2 * t], w1 = tkw[2 * t + 1];
    const u16x8 y0 = *(const u16x8*)(ybuf + (size_t)p0 * H_ + c8);
    const u16x8 y1 = *(const u16x8*)(ybuf + (size_t)p1 * H_ + c8);
    float o[8];
#pragma unroll
    for (int j = 0; j < 8; ++j) {
        const unsigned f0 = ((unsigned)y0[j]) << 16;
        const unsigned f1 = ((unsigned)y1[j]) << 16;
        o[j] = w0 * __uint_as_float(f0) + w1 * __uint_as_float(f1);
    }
    float* dst = out + (size_t)t * H_ + c8;
    *(float4*)dst       = make_float4(o[0], o[1], o[2], o[3]);
    *(float4*)(dst + 4) = make_float4(o[4], o[5], o[6], o[7]);
}

// ---------------------------------------------------------------- launch ----
extern "C" void kernel_launch(void* const* d_in, const int* in_sizes, int n_in,
                              void* d_out, int out_size, void* d_ws, size_t ws_size,
                              hipStream_t stream) {
    const float* x   = (const float*)d_in[0];
    const int*   tki = (const int*)d_in[1];
    const float* tkw = (const float*)d_in[2];
    const float* wg  = (const float*)d_in[3];
    const float* wd  = (const float*)d_in[4];
    float* out = (float*)d_out;

    // ws layout (all 16B-aligned)
    char* p = (char*)d_ws;
    int* counts = (int*)p;  p += 32;
    int* bases  = (int*)p;  p += 32;
    int* tok    = (int*)p;  p += NPAIR * sizeof(int);
    int* inv    = (int*)p;  p += NPAIR * sizeof(int);
    ushort* xb   = (ushort*)p; p += (size_t)S_ * H_ * 2;              // 8 MB
    ushort* hbuf = (ushort*)p; p += (size_t)NPAIR * I_ * 2;           // 11.5 MB
    ushort* ybuf = (ushort*)p; p += (size_t)NPAIR * H_ * 2;           // 16.8 MB
    ushort* wgt  = (ushort*)p; p += (size_t)E_ * (2 * I_) * H_ * 2;   // 92.3 MB
    ushort* wdt  = (ushort*)p; p += (size_t)E_ * H_ * I_ * 2;         // 46.1 MB
    const size_t need = (size_t)(p - (char*)d_ws);

    convert_x<<<dim3((S_ * H_) / (256 * 8)), 256, 0, stream>>>(x, xb);
    moe_router<<<dim3(1), 256, 0, stream>>>(tki, counts, bases, tok, inv);

    if (ws_size >= need) {
        // bf16-weight fast path (global_load_lds staging, no hot-loop cvt)
        convert_w<<<dim3(E_ * NT1 * KT1 + E_ * NT2 * KT2), 256, 0, stream>>>(wg, wd, wgt, wdt);
        moe_gemm1<<<dim3(I_ / 128, E_ * MAXMT), 256, 0, stream>>>(xb, wgt, counts, bases, tok, hbuf);
        moe_gemm2<<<dim3(H_ / 128, E_ * MAXMT), 256, 0, stream>>>(hbuf, wdt, counts, bases, ybuf);
    } else {
        // verified fp32-weight path (previous session, ~426 us)
        moe_gemm1_f32<<<dim3(I_ / 128, E_ * MAXMT), 256, 0, stream>>>(xb, wg, counts, bases, tok, hbuf);
        moe_gemm2_f32<<<dim3(H_ / 128, E_ * MAXMT), 256, 0, stream>>>(hbuf, wd, counts, bases, ybuf);
    }
    moe_combine<<<dim3(S_), 256, 0, stream>>>(ybuf, inv, tkw, out);
}

// Round 3
// 474.031 us; speedup vs baseline: 1.0409x; 1.0409x over previous
//
#include <hip/hip_runtime.h>
#include <hip/hip_bf16.h>

#define E_ 8
#define H_ 2048
#define I_ 1408
#define S_ 2048       // B*S tokens
#define NPAIR 4096    // S_*K
#define MAXMT 32      // worst-case M-tiles per expert (4096/128)

#define KT1 64        // H_/32  k-steps in gemm1
#define KT2 44        // I_/32  k-steps in gemm2

// convert grid partitions (each block converts 2048 elements)
#define WGBLK 22528   // E_*2*I_*H_/2048
#define WDBLK 11264   // E_*H_*I_/2048
#define XBLK   2048   // S_*H_/2048

typedef short bf16x8 __attribute__((ext_vector_type(8)));
typedef ushort u16x8 __attribute__((ext_vector_type(8)));
typedef float f32x4  __attribute__((ext_vector_type(4)));

__device__ inline bf16x8 pack8(float4 a, float4 b) {
    bf16x8 r;
    const float v[8] = {a.x, a.y, a.z, a.w, b.x, b.y, b.z, b.w};
#pragma unroll
    for (int j = 0; j < 8; ++j) {
        __hip_bfloat16 t = __float2bfloat16(v[j]);
        r[j] = *reinterpret_cast<short*>(&t);
    }
    return r;
}

// async global->LDS, 16B per lane; LDS dest linear (base + lane*16),
// global source is per-lane (may be strided/gathered)
__device__ __forceinline__ void gload16(const ushort* g, ushort* l) {
    __builtin_amdgcn_global_load_lds(
        (const __attribute__((address_space(1))) void*)g,
        (__attribute__((address_space(3))) void*)l,
        16, 0, 0);
}

// ------------------------------------------- fused convert + router ----
// blocks [0,WGBLK): wg fp32->bf16 (row-major, streaming)
// blocks [WGBLK,WGBLK+WDBLK): wd
// blocks [...,+XBLK): x
// last block: router
__global__ __launch_bounds__(256)
void convert_all(const float* __restrict__ wg, const float* __restrict__ wd,
                 const float* __restrict__ x, const int* __restrict__ tki,
                 ushort* __restrict__ wgb, ushort* __restrict__ wdb,
                 ushort* __restrict__ xb,
                 int* __restrict__ counts, int* __restrict__ bases,
                 int* __restrict__ tok, int* __restrict__ inv) {
    const int b = blockIdx.x;
    const int tid = threadIdx.x;
    if (b < WGBLK + WDBLK + XBLK) {
        const float* src;
        ushort* dst;
        size_t off;
        if (b < WGBLK)              { src = wg; dst = wgb; off = (size_t)b * 2048; }
        else if (b < WGBLK + WDBLK) { src = wd; dst = wdb; off = (size_t)(b - WGBLK) * 2048; }
        else                        { src = x;  dst = xb;  off = (size_t)(b - WGBLK - WDBLK) * 2048; }
        const size_t i = off + (size_t)tid * 8;
        const float4 a = *(const float4*)(src + i);
        const float4 c = *(const float4*)(src + i + 4);
        *(bf16x8*)(dst + i) = pack8(a, c);
        return;
    }
    // ------- router (single block) -------
    __shared__ int cnt[E_];
    __shared__ int cur[E_];
    if (tid < E_) cnt[tid] = 0;
    __syncthreads();
    for (int p = tid; p < NPAIR; p += 256)
        atomicAdd(&cnt[tki[p]], 1);
    __syncthreads();
    if (tid == 0) {
        int bb = 0;
        for (int e = 0; e < E_; ++e) {
            counts[e] = cnt[e];
            bases[e]  = bb;
            cur[e]    = bb;
            bb += cnt[e];
        }
    }
    __syncthreads();
    for (int p = tid; p < NPAIR; p += 256) {
        const int e = tki[p];
        const int pos = atomicAdd(&cur[e], 1);
        tok[pos] = p >> 1;   // token id (K=2)
        inv[p]   = pos;      // pair -> sorted position
    }
}

// ------------------------------------------------ GEMM1 (bf16 weights) ----
// X_gathered(count x 2048) @ gate_up[e]^T, fused SiLU(gate)*up -> h bf16.
// Double-buffered LDS + counted vmcnt: next tile's loads stay in flight
// across the barrier (T3/T4 minimum 2-phase).
__global__ __launch_bounds__(256, 2)
void moe_gemm1(const ushort* __restrict__ xb,
               const ushort* __restrict__ wgb,
               const int* __restrict__ counts,
               const int* __restrict__ bases,
               const int* __restrict__ tok,
               ushort* __restrict__ hbuf) {
    const int e  = blockIdx.y & (E_ - 1);
    const int mt = blockIdx.y >> 3;          // mt-major: B-sharing blocks 88 apart (same XCD)
    const int count = counts[e];
    if (mt * 128 >= count) return;
    const int base = bases[e];
    const int nt = blockIdx.x;               // 0..10
    const int n0 = nt * 128;
    const ushort* wgbe = wgb + (size_t)e * (2 * I_) * H_;

    // dbuf: 2 x (A,G,U) x 128x32 bf16 = 48 KB; epilogue Ht (34 KB) overlays
    __shared__ alignas(16) ushort sm[24576];

    const int tid  = threadIdx.x;
    const int lane = tid & 63;
    const int wid  = tid >> 6;
    const int wm = wid & 1, wn = wid >> 1;
    const int lr = lane & 15, lq = lane >> 4;

    const f32x4 vzero = {0.f, 0.f, 0.f, 0.f};
    f32x4 accg[4][4], accu[4][4];
#pragma unroll
    for (int mi = 0; mi < 4; ++mi)
#pragma unroll
        for (int ni = 0; ni < 4; ++ni) { accg[mi][ni] = vzero; accu[mi][ni] = vzero; }

    // staging: chunk c=tid covers LDS row c>>2, cols (c&3)*8; c=tid+256 -> +64 rows
    const int srow = tid >> 2;          // 0..63
    const int sc8  = (tid & 3) * 8;
    const int ia0 = mt * 128 + srow, ia1 = ia0 + 64;
    const ushort* ap0 = xb + (size_t)(ia0 < count ? tok[base + ia0] : 0) * H_ + sc8;
    const ushort* ap1 = xb + (size_t)(ia1 < count ? tok[base + ia1] : 0) * H_ + sc8;
    const ushort* gp0 = wgbe + (size_t)(n0 + srow) * H_ + sc8;
    const ushort* gp1 = gp0 + (size_t)64 * H_;
    const ushort* up0 = wgbe + (size_t)(I_ + n0 + srow) * H_ + sc8;
    const ushort* up1 = up0 + (size_t)64 * H_;

    const int d0 = tid * 8, d1 = tid * 8 + 2048;

    // prologue: tile 0 -> buf 0
    {
        ushort* bA = sm; ushort* bG = sm + 4096; ushort* bU = sm + 8192;
        gload16(ap0, bA + d0); gload16(ap1, bA + d1);
        gload16(gp0, bG + d0); gload16(gp1, bG + d1);
        gload16(up0, bU + d0); gload16(up1, bU + d1);
    }

    for (int kt = 0; kt < KT1; ++kt) {
        ushort* curb = sm + (kt & 1) * 12288;
        if (kt + 1 < KT1) {
            ap0 += 32; ap1 += 32; gp0 += 32; gp1 += 32; up0 += 32; up1 += 32;
            ushort* nb = sm + ((kt + 1) & 1) * 12288;
            gload16(ap0, nb + d0);        gload16(ap1, nb + d1);
            gload16(gp0, nb + 4096 + d0); gload16(gp1, nb + 4096 + d1);
            gload16(up0, nb + 8192 + d0); gload16(up1, nb + 8192 + d1);
            asm volatile("s_waitcnt vmcnt(6)" ::: "memory");   // tile kt done
        } else {
            asm volatile("s_waitcnt vmcnt(0)" ::: "memory");
        }
        __builtin_amdgcn_s_barrier();
        __builtin_amdgcn_sched_barrier(0);

        const ushort* As = curb;
        const ushort* Bg = curb + 4096;
        const ushort* Bu = curb + 8192;
        bf16x8 a[4], bg[4], bu[4];
#pragma unroll
        for (int mi = 0; mi < 4; ++mi)
            a[mi] = *(const bf16x8*)&As[(wm * 64 + mi * 16 + lr) * 32 + lq * 8];
#pragma unroll
        for (int ni = 0; ni < 4; ++ni) {
            bg[ni] = *(const bf16x8*)&Bg[(wn * 64 + ni * 16 + lr) * 32 + lq * 8];
            bu[ni] = *(const bf16x8*)&Bu[(wn * 64 + ni * 16 + lr) * 32 + lq * 8];
        }
#pragma unroll
        for (int mi = 0; mi < 4; ++mi)
#pragma unroll
            for (int ni = 0; ni < 4; ++ni) {
                accg[mi][ni] = __builtin_amdgcn_mfma_f32_16x16x32_bf16(a[mi], bg[ni], accg[mi][ni], 0, 0, 0);
                accu[mi][ni] = __builtin_amdgcn_mfma_f32_16x16x32_bf16(a[mi], bu[ni], accu[mi][ni], 0, 0, 0);
            }
        __builtin_amdgcn_sched_barrier(0);
        __builtin_amdgcn_s_barrier();
    }

    // epilogue: silu(g)*u -> bf16 tile in LDS (stride 136) -> coalesced stores
    ushort* Ht = sm;
#pragma unroll
    for (int mi = 0; mi < 4; ++mi)
#pragma unroll
        for (int r = 0; r < 4; ++r) {
            const int row = wm * 64 + mi * 16 + lq * 4 + r;
#pragma unroll
            for (int ni = 0; ni < 4; ++ni) {
                const int col = wn * 64 + ni * 16 + lr;
                const float g = accg[mi][ni][r];
                const float u = accu[mi][ni][r];
                const float h = (g / (1.0f + __expf(-g))) * u;
                __hip_bfloat16 hb = __float2bfloat16(h);
                Ht[row * 136 + col] = *reinterpret_cast<ushort*>(&hb);
            }
        }
    __syncthreads();
#pragma unroll
    for (int p = 0; p < 8; ++p) {
        const int slot = p * 256 + tid;
        const int row = slot >> 4;
        const int cc  = (slot & 15) * 8;
        const int gi = mt * 128 + row;
        if (gi < count)
            *(uint4*)&hbuf[(size_t)(base + gi) * I_ + n0 + cc] = *(const uint4*)&Ht[row * 136 + cc];
    }
}

// ------------------------------------------------ GEMM2 (bf16 weights) ----
__global__ __launch_bounds__(256, 2)
void moe_gemm2(const ushort* __restrict__ hbuf,
               const ushort* __restrict__ wdb,
               const int* __restrict__ counts,
               const int* __restrict__ bases,
               ushort* __restrict__ ybuf) {
    const int e  = blockIdx.y & (E_ - 1);
    const int mt = blockIdx.y >> 3;
    const int count = counts[e];
    if (mt * 128 >= count) return;
    const int base = bases[e];
    const int nt = blockIdx.x;               // 0..15
    const int n0 = nt * 128;
    const ushort* wdbe = wdb + (size_t)e * H_ * I_;

    // dbuf: 2 x (A,B) x 128x32 = 32 KB; epilogue Yt needs 34 KB -> sm[17408]
    __shared__ alignas(16) ushort sm[17408];

    const int tid  = threadIdx.x;
    const int lane = tid & 63;
    const int wid  = tid >> 6;
    const int wm = wid & 1, wn = wid >> 1;
    const int lr = lane & 15, lq = lane >> 4;

    const f32x4 vzero = {0.f, 0.f, 0.f, 0.f};
    f32x4 acc[4][4];
#pragma unroll
    for (int mi = 0; mi < 4; ++mi)
#pragma unroll
        for (int ni = 0; ni < 4; ++ni) acc[mi][ni] = vzero;

    const int srow = tid >> 2;
    const int sc8  = (tid & 3) * 8;
    const int ia0 = mt * 128 + srow, ia1 = ia0 + 64;
    const ushort* ap0 = hbuf + (size_t)(base + (ia0 < count ? ia0 : 0)) * I_ + sc8;
    const ushort* ap1 = hbuf + (size_t)(base + (ia1 < count ? ia1 : 0)) * I_ + sc8;
    const ushort* bp0 = wdbe + (size_t)(n0 + srow) * I_ + sc8;
    const ushort* bp1 = bp0 + (size_t)64 * I_;

    const int d0 = tid * 8, d1 = tid * 8 + 2048;

    {
        ushort* bA = sm; ushort* bB = sm + 4096;
        gload16(ap0, bA + d0); gload16(ap1, bA + d1);
        gload16(bp0, bB + d0); gload16(bp1, bB + d1);
    }

    for (int kt = 0; kt < KT2; ++kt) {
        ushort* curb = sm + (kt & 1) * 8192;
        if (kt + 1 < KT2) {
            ap0 += 32; ap1 += 32; bp0 += 32; bp1 += 32;
            ushort* nb = sm + ((kt + 1) & 1) * 8192;
            gload16(ap0, nb + d0);        gload16(ap1, nb + d1);
            gload16(bp0, nb + 4096 + d0); gload16(bp1, nb + 4096 + d1);
            asm volatile("s_waitcnt vmcnt(4)" ::: "memory");
        } else {
            asm volatile("s_waitcnt vmcnt(0)" ::: "memory");
        }
        __builtin_amdgcn_s_barrier();
        __builtin_amdgcn_sched_barrier(0);

        const ushort* As = curb;
        const ushort* Bs = curb + 4096;
        bf16x8 a[4], b[4];
#pragma unroll
        for (int mi = 0; mi < 4; ++mi)
            a[mi] = *(const bf16x8*)&As[(wm * 64 + mi * 16 + lr) * 32 + lq * 8];
#pragma unroll
        for (int ni = 0; ni < 4; ++ni)
            b[ni] = *(const bf16x8*)&Bs[(wn * 64 + ni * 16 + lr) * 32 + lq * 8];
#pragma unroll
        for (int mi = 0; mi < 4; ++mi)
#pragma unroll
            for (int ni = 0; ni < 4; ++ni)
                acc[mi][ni] = __builtin_amdgcn_mfma_f32_16x16x32_bf16(a[mi], b[ni], acc[mi][ni], 0, 0, 0);
        __builtin_amdgcn_sched_barrier(0);
        __builtin_amdgcn_s_barrier();
    }

    ushort* Yt = sm;
#pragma unroll
    for (int mi = 0; mi < 4; ++mi)
#pragma unroll
        for (int r = 0; r < 4; ++r) {
            const int row = wm * 64 + mi * 16 + lq * 4 + r;
#pragma unroll
            for (int ni = 0; ni < 4; ++ni) {
                const int col = wn * 64 + ni * 16 + lr;
                __hip_bfloat16 yb = __float2bfloat16(acc[mi][ni][r]);
                Yt[row * 136 + col] = *reinterpret_cast<ushort*>(&yb);
            }
        }
    __syncthreads();
#pragma unroll
    for (int p = 0; p < 8; ++p) {
        const int slot = p * 256 + tid;
        const int row = slot >> 4;
        const int cc  = (slot & 15) * 8;
        const int gi = mt * 128 + row;
        if (gi < count)
            *(uint4*)&ybuf[(size_t)(base + gi) * H_ + n0 + cc] = *(const uint4*)&Yt[row * 136 + cc];
    }
}

// --------------------------------------------------------------- combine ----
__global__ void moe_combine(const ushort* __restrict__ ybuf,
                            const int* __restrict__ inv,
                            const float* __restrict__ tkw,
                            float* __restrict__ out) {
    const int t = blockIdx.x;
    const int c8 = threadIdx.x * 8;
    const int p0 = inv[2 * t], p1 = inv[2 * t + 1];
    const float w0 = tkw[2 * t], w1 = tkw[2 * t + 1];
    const u16x8 y0 = *(const u16x8*)(ybuf + (size_t)p0 * H_ + c8);
    const u16x8 y1 = *(const u16x8*)(ybuf + (size_t)p1 * H_ + c8);
    float o[8];
#pragma unroll
    for (int j = 0; j < 8; ++j) {
        const unsigned f0 = ((unsigned)y0[j]) << 16;
        const unsigned f1 = ((unsigned)y1[j]) << 16;
        o[j] = w0 * __uint_as_float(f0) + w1 * __uint_as_float(f1);
    }
    float* dst = out + (size_t)t * H_ + c8;
    *(float4*)dst       = make_float4(o[0], o[1], o[2], o[3]);
    *(float4*)(dst + 4) = make_float4(o[4], o[5], o[6], o[7]);
}

// ---------------------------------------------------------------- launch ----
extern "C" void kernel_launch(void* const* d_in, const int* in_sizes, int n_in,
                              void* d_out, int out_size, void* d_ws, size_t ws_size,
                              hipStream_t stream) {
    const float* x   = (const float*)d_in[0];
    const int*   tki = (const int*)d_in[1];
    const float* tkw = (const float*)d_in[2];
    const float* wg  = (const float*)d_in[3];
    const float* wd  = (const float*)d_in[4];
    float* out = (float*)d_out;

    // ws layout (all 16B-aligned); proven to fit in round 2 (fast path ran)
    char* p = (char*)d_ws;
    int* counts = (int*)p;  p += 32;
    int* bases  = (int*)p;  p += 32;
    int* tok    = (int*)p;  p += NPAIR * sizeof(int);
    int* inv    = (int*)p;  p += NPAIR * sizeof(int);
    ushort* xb   = (ushort*)p; p += (size_t)S_ * H_ * 2;              // 8 MB
    ushort* hbuf = (ushort*)p; p += (size_t)NPAIR * I_ * 2;           // 11.5 MB
    ushort* ybuf = (ushort*)p; p += (size_t)NPAIR * H_ * 2;           // 16.8 MB
    ushort* wgb  = (ushort*)p; p += (size_t)E_ * (2 * I_) * H_ * 2;   // 92.3 MB (row-major bf16)
    ushort* wdb  = (ushort*)p; p += (size_t)E_ * H_ * I_ * 2;         // 46.1 MB (row-major bf16)

    convert_all<<<dim3(WGBLK + WDBLK + XBLK + 1), 256, 0, stream>>>(
        wg, wd, x, tki, wgb, wdb, xb, counts, bases, tok, inv);
    moe_gemm1<<<dim3(I_ / 128, E_ * MAXMT), 256, 0, stream>>>(xb, wgb, counts, bases, tok, hbuf);
    moe_gemm2<<<dim3(H_ / 128, E_ * MAXMT), 256, 0, stream>>>(hbuf, wdb, counts, bases, ybuf);
    moe_combine<<<dim3(S_), 256, 0, stream>>>(ybuf, inv, tkw, out);
}